// Round 3
// baseline (682.327 us; speedup 1.0000x reference)
//
#include <hip/hip_runtime.h>

#define NBINS   10
#define NCOPY   32            // one histogram copy per (lane & 31): <=2 lanes/copy
#define CSTRIDE 21            // dwords/copy: 10 sums + 10 counts + 1 pad (odd -> full bank spread)
#define BLOCK   256
#define GRID    2048

// ws layout: double gsum[10] ; unsigned gcnt[10]
__global__ void ghm_init(double* gsum, unsigned* gcnt) {
    int t = threadIdx.x;
    if (t < NBINS) { gsum[t] = 0.0; gcnt[t] = 0u; }
}

__global__ __launch_bounds__(BLOCK) void ghm_main(const float4* __restrict__ pred,
                                                  const float4* __restrict__ targ,
                                                  int n4,
                                                  double* __restrict__ gsum,
                                                  unsigned* __restrict__ gcnt) {
    __shared__ float hist[NCOPY * CSTRIDE];   // [copy][0..9]=bce sums, [copy][10..19]=counts

    for (int j = threadIdx.x; j < NCOPY * CSTRIDE; j += BLOCK) hist[j] = 0.0f;
    __syncthreads();

    float* const mybase = &hist[(threadIdx.x & (NCOPY - 1)) * CSTRIDE];

    int i = blockIdx.x * BLOCK + threadIdx.x;
    const int stride = GRID * BLOCK;

    for (; i < n4; i += stride) {
        float4 p = pred[i];
        float4 t = targ[i];

        // Identities (exact for t in {0,1}):  x' = x*(1-2t)
        //   g   = |sigmoid(x) - t| = sigmoid(x')
        //   bce = max(x,0) - x*t + log1p(exp(-|x|)) = softplus(x') = max(x',0) + log(1+exp(-|x'|))
#define ELEM(px, tx)                                                         \
        {                                                                    \
            float x  = (px);                                                 \
            float s2 = fmaf(-2.0f, (tx), 1.0f);      /* 1-2t: exactly ±1 */  \
            float xp = x * s2;                       /* x' (exact) */        \
            float e  = __expf(-fabsf(xp));           /* exp(-|x'|) */        \
            float d  = 1.0f + e;                                             \
            float r  = __builtin_amdgcn_rcpf(d);                             \
            float g  = (xp >= 0.0f ? 1.0f : e) * r;  /* sigmoid(x') */       \
            int   bin = (int)(g * 10.0f);                                    \
            bin = bin > 9 ? 9 : bin;                                         \
            float bce = fmaxf(xp, 0.0f) + __logf(d);                         \
            float* q = mybase + bin;                                         \
            atomicAdd(q, bce);          /* ds_add_f32, fire-and-forget */    \
            atomicAdd(q + NBINS, 1.0f); /* count (f32 exact: <=4096/copy) */ \
        }

        ELEM(p.x, t.x)
        ELEM(p.y, t.y)
        ELEM(p.z, t.z)
        ELEM(p.w, t.w)
#undef ELEM
    }

    __syncthreads();

    if (threadIdx.x < NBINS) {
        float s = 0.0f, c = 0.0f;
#pragma unroll
        for (int cp = 0; cp < NCOPY; ++cp) {
            s += hist[cp * CSTRIDE + threadIdx.x];
            c += hist[cp * CSTRIDE + NBINS + threadIdx.x];
        }
        atomicAdd(&gsum[threadIdx.x], (double)s);
        atomicAdd(&gcnt[threadIdx.x], (unsigned)c);
    }
}

__global__ void ghm_finalize(const double* __restrict__ gsum,
                             const unsigned* __restrict__ gcnt,
                             float* __restrict__ out) {
    if (threadIdx.x == 0 && blockIdx.x == 0) {
        double acc = 0.0;
        int n = 0;
        for (int b = 0; b < NBINS; ++b) {
            unsigned c = gcnt[b];
            if (c > 0u) {
                ++n;
                acc += gsum[b] / (double)c;
            }
        }
        if (n < 1) n = 1;
        out[0] = (float)(acc / (double)n);
    }
}

extern "C" void kernel_launch(void* const* d_in, const int* in_sizes, int n_in,
                              void* d_out, int out_size, void* d_ws, size_t ws_size,
                              hipStream_t stream) {
    const float4* pred = (const float4*)d_in[0];
    const float4* targ = (const float4*)d_in[1];
    double*   gsum = (double*)d_ws;
    unsigned* gcnt = (unsigned*)((char*)d_ws + NBINS * sizeof(double));
    float* out = (float*)d_out;

    int n4 = in_sizes[0] / 4;

    ghm_init<<<1, 64, 0, stream>>>(gsum, gcnt);
    ghm_main<<<GRID, BLOCK, 0, stream>>>(pred, targ, n4, gsum, gcnt);
    ghm_finalize<<<1, 64, 0, stream>>>(gsum, gcnt, out);
}

// Round 4
// 143.216 us; speedup vs baseline: 4.7643x; 4.7643x over previous
//
#include <hip/hip_runtime.h>

#define NBINS 10
#define BLOCK 256
#define GRID  2048
#define NWAVE (BLOCK / 64)

// ws layout: double gU[10] ; unsigned gC[10]
// Cumulative form: gU[0] = sum of ALL bce, gU[1+j] = sum of bce where xp >= TAU[j]
//                  gC[0] = total count,    gC[1+j] = count where xp >= TAU[j]
// Per-bin: S_b = gU[b] - gU[b+1], c_b = gC[b] - gC[b+1]  (with [10] == 0)

__global__ void ghm_init(double* gU, unsigned* gC) {
    int t = threadIdx.x;
    if (t < NBINS) { gU[t] = 0.0; gC[t] = 0u; }
}

__global__ __launch_bounds__(BLOCK) void ghm_main(const float4* __restrict__ pred,
                                                  const float4* __restrict__ targ,
                                                  int n4,
                                                  double* __restrict__ gU,
                                                  unsigned* __restrict__ gC) {
    // TAU[j] = logit((j+1)/10): bin(x') >= j+1  <=>  x' >= TAU[j]
    const float TAU[9] = {-2.19722458f, -1.38629436f, -0.84729786f, -0.40546511f, 0.0f,
                           0.40546511f,  0.84729786f,  1.38629436f,  2.19722458f};

    float U[10];
#pragma unroll
    for (int k = 0; k < 10; ++k) U[k] = 0.0f;
    int C[9];                       // wave-uniform (ballot-derived) -> SGPRs
#pragma unroll
    for (int j = 0; j < 9; ++j) C[j] = 0;
    int quads = 0;

    int i = blockIdx.x * BLOCK + threadIdx.x;
    const int stride = GRID * BLOCK;

    for (; i < n4; i += stride) {
        float4 p = pred[i];
        float4 t = targ[i];
        ++quads;

        // x' = x*(1-2t) (exact for t in {0,1}):
        //   |sigmoid(x)-t| = sigmoid(x'),  bce = softplus(x') = max(x',0)+ln2*log2(1+2^(-|x'|*log2e))
#define ELEM(px, tx)                                                          \
        {                                                                     \
            float x  = (px);                                                  \
            float xp = x * fmaf(-2.0f, (tx), 1.0f);                           \
            float y  = fabsf(xp) * -1.44269504f;    /* -|x'|*log2(e) */       \
            float e2 = __builtin_amdgcn_exp2f(y);   /* e^{-|x'|} */           \
            float l2 = __builtin_amdgcn_logf(1.0f + e2);  /* log2(1+e) */     \
            float bce = fmaf(0.69314718f, l2, fmaxf(xp, 0.0f));               \
            U[0] += bce;                                                      \
            _Pragma("unroll")                                                 \
            for (int j = 0; j < 9; ++j) {                                     \
                bool pg = (xp >= TAU[j]);                                     \
                C[j] += __popcll(__ballot(pg));  /* wave-uniform -> scalar */ \
                U[1 + j] += pg ? bce : 0.0f;                                  \
            }                                                                 \
        }

        ELEM(p.x, t.x)
        ELEM(p.y, t.y)
        ELEM(p.z, t.z)
        ELEM(p.w, t.w)
#undef ELEM
    }

    // Wave butterfly for the per-lane float accumulators + element count.
#pragma unroll
    for (int k = 0; k < 10; ++k) {
#pragma unroll
        for (int m = 1; m < 64; m <<= 1) U[k] += __shfl_xor(U[k], m, 64);
    }
    for (int m = 1; m < 64; m <<= 1) quads += __shfl_xor(quads, m, 64);

    __shared__ float sU[NWAVE][NBINS];
    __shared__ int   sC[NWAVE][NBINS];
    const int wid  = threadIdx.x >> 6;
    const int lane = threadIdx.x & 63;
    if (lane == 0) {
#pragma unroll
        for (int k = 0; k < 10; ++k) sU[wid][k] = U[k];
        sC[wid][0] = quads * 4;     // total elements this wave
#pragma unroll
        for (int j = 0; j < 9; ++j) sC[wid][1 + j] = C[j];
    }
    __syncthreads();

    if (threadIdx.x < NBINS) {
        float s = 0.0f;
        int   c = 0;
#pragma unroll
        for (int w = 0; w < NWAVE; ++w) {
            s += sU[w][threadIdx.x];
            c += sC[w][threadIdx.x];
        }
        atomicAdd(&gU[threadIdx.x], (double)s);
        atomicAdd(&gC[threadIdx.x], (unsigned)c);
    }
}

__global__ void ghm_finalize(const double* __restrict__ gU,
                             const unsigned* __restrict__ gC,
                             float* __restrict__ out) {
    if (threadIdx.x == 0 && blockIdx.x == 0) {
        double acc = 0.0;
        int n = 0;
        for (int b = 0; b < NBINS; ++b) {
            double   S = gU[b] - (b < 9 ? gU[b + 1] : 0.0);
            unsigned c = gC[b] - (b < 9 ? gC[b + 1] : 0u);
            if (c > 0u) {
                ++n;
                acc += S / (double)c;
            }
        }
        if (n < 1) n = 1;
        out[0] = (float)(acc / (double)n);
    }
}

extern "C" void kernel_launch(void* const* d_in, const int* in_sizes, int n_in,
                              void* d_out, int out_size, void* d_ws, size_t ws_size,
                              hipStream_t stream) {
    const float4* pred = (const float4*)d_in[0];
    const float4* targ = (const float4*)d_in[1];
    double*   gU = (double*)d_ws;
    unsigned* gC = (unsigned*)((char*)d_ws + NBINS * sizeof(double));
    float* out = (float*)d_out;

    int n4 = in_sizes[0] / 4;

    ghm_init<<<1, 64, 0, stream>>>(gU, gC);
    ghm_main<<<GRID, BLOCK, 0, stream>>>(pred, targ, n4, gU, gC);
    ghm_finalize<<<1, 64, 0, stream>>>(gU, gC, out);
}

// Round 5
// 132.192 us; speedup vs baseline: 5.1616x; 1.0834x over previous
//
#include <hip/hip_runtime.h>

#define NBINS 10
#define BLOCK 256
#define GRID  2048
#define NWAVE (BLOCK / 64)

// Cumulative form: U[0] = sum of ALL bce, U[j] (j>=1) = sum of bce where xp >= TAU[j-1]
//                  C[j] (j>=1) = count where xp >= TAU[j-1]; C[0] = total (known = n elements)
// Per-bin: S_b = U[b] - U[b+1], c_b = C[b] - C[b+1]  (with [10] == 0)
// ws layout: double gU[10] ; unsigned gC[10]

__global__ void ghm_init(double* gU, unsigned* gC) {
    int t = threadIdx.x;
    if (t < NBINS) { gU[t] = 0.0; gC[t] = 0u; }
}

__global__ __launch_bounds__(BLOCK) void ghm_main(const float4* __restrict__ pred,
                                                  const float4* __restrict__ targ,
                                                  int n4,
                                                  double* __restrict__ gU,
                                                  unsigned* __restrict__ gC) {
    // TAU[j] = logit((j+1)/10): bin(x') >= j+1  <=>  x' >= TAU[j]
    const float TAU[9] = {-2.19722458f, -1.38629436f, -0.84729786f, -0.40546511f, 0.0f,
                           0.40546511f,  0.84729786f,  1.38629436f,  2.19722458f};

    float U0 = 0.0f;
    float    Uc[9];
    unsigned Cc[9];
#pragma unroll
    for (int j = 0; j < 9; ++j) { Uc[j] = 0.0f; Cc[j] = 0u; }

    const int stride = GRID * BLOCK;
    int i = blockIdx.x * BLOCK + threadIdx.x;

    // x' = x*(1-2t) (exact for t in {0,1}):
    //   |sigmoid(x)-t| = sigmoid(x'),  bce = softplus(x') = max(x',0)+ln2*log2(1+2^(-|x'|*log2e))
#define ELEM(px, tx)                                                          \
        {                                                                     \
            float x  = (px);                                                  \
            float xp = x * fmaf(-2.0f, (tx), 1.0f);                           \
            float y  = fabsf(xp) * -1.44269504f;                              \
            float e2 = __builtin_amdgcn_exp2f(y);        /* e^{-|x'|} */      \
            float l2 = __builtin_amdgcn_logf(1.0f + e2); /* log2(1+e) */      \
            float bce = fmaf(0.69314718f, l2, fmaxf(xp, 0.0f));               \
            U0 += bce;                                                        \
            _Pragma("unroll")                                                 \
            for (int j = 0; j < 9; ++j) {                                     \
                bool pg = (xp >= TAU[j]);                                     \
                Uc[j] += pg ? bce : 0.0f;   /* cndmask + add (vcc) */         \
                Cc[j] += pg ? 1u : 0u;      /* v_addc_co_u32 (vcc reuse) */   \
            }                                                                 \
        }

    // Unroll x2: 4 global_load_dwordx4 in flight per iteration.
    for (; i < n4; i += 2 * stride) {
        float4 p0 = pred[i];
        float4 t0 = targ[i];
        float4 p1 = pred[i + stride];
        float4 t1 = targ[i + stride];

        ELEM(p0.x, t0.x) ELEM(p0.y, t0.y) ELEM(p0.z, t0.z) ELEM(p0.w, t0.w)
        ELEM(p1.x, t1.x) ELEM(p1.y, t1.y) ELEM(p1.z, t1.z) ELEM(p1.w, t1.w)
    }
#undef ELEM

    // Wave butterfly reduction.
#pragma unroll
    for (int m = 1; m < 64; m <<= 1) U0 += __shfl_xor(U0, m, 64);
#pragma unroll
    for (int j = 0; j < 9; ++j) {
#pragma unroll
        for (int m = 1; m < 64; m <<= 1) {
            Uc[j] += __shfl_xor(Uc[j], m, 64);
            Cc[j] += __shfl_xor(Cc[j], m, 64);
        }
    }

    __shared__ float    sU[NWAVE][NBINS];
    __shared__ unsigned sC[NWAVE][NBINS];
    const int wid  = threadIdx.x >> 6;
    const int lane = threadIdx.x & 63;
    if (lane == 0) {
        sU[wid][0] = U0;
        sC[wid][0] = 0u;
#pragma unroll
        for (int j = 0; j < 9; ++j) { sU[wid][1 + j] = Uc[j]; sC[wid][1 + j] = Cc[j]; }
    }
    __syncthreads();

    if (threadIdx.x < NBINS) {
        float    s = 0.0f;
        unsigned c = 0u;
#pragma unroll
        for (int w = 0; w < NWAVE; ++w) {
            s += sU[w][threadIdx.x];
            c += sC[w][threadIdx.x];
        }
        atomicAdd(&gU[threadIdx.x], (double)s);
        if (threadIdx.x > 0) atomicAdd(&gC[threadIdx.x], c);
    }
}

__global__ void ghm_finalize(const double* __restrict__ gU,
                             const unsigned* __restrict__ gC,
                             float* __restrict__ out, unsigned ntot) {
    if (threadIdx.x == 0 && blockIdx.x == 0) {
        double acc = 0.0;
        int n = 0;
        for (int b = 0; b < NBINS; ++b) {
            double   hiU = (b < 9) ? gU[b + 1] : 0.0;
            unsigned hiC = (b < 9) ? gC[b + 1] : 0u;
            double   loU = gU[b];
            unsigned loC = (b == 0) ? ntot : gC[b];
            double   S = loU - hiU;
            unsigned c = loC - hiC;
            if (c > 0u) {
                ++n;
                acc += S / (double)c;
            }
        }
        if (n < 1) n = 1;
        out[0] = (float)(acc / (double)n);
    }
}

extern "C" void kernel_launch(void* const* d_in, const int* in_sizes, int n_in,
                              void* d_out, int out_size, void* d_ws, size_t ws_size,
                              hipStream_t stream) {
    const float4* pred = (const float4*)d_in[0];
    const float4* targ = (const float4*)d_in[1];
    double*   gU = (double*)d_ws;
    unsigned* gC = (unsigned*)((char*)d_ws + NBINS * sizeof(double));
    float* out = (float*)d_out;

    int n4 = in_sizes[0] / 4;
    unsigned ntot = (unsigned)in_sizes[0];

    ghm_init<<<1, 64, 0, stream>>>(gU, gC);
    ghm_main<<<GRID, BLOCK, 0, stream>>>(pred, targ, n4, gU, gC);
    ghm_finalize<<<1, 64, 0, stream>>>(gU, gC, out, ntot);
}